// Round 1
// baseline (970.234 us; speedup 1.0000x reference)
//
#include <hip/hip_runtime.h>
#include <hip/hip_bf16.h>

#define BATCH 8
#define HDIM 64
#define WDIM 64
#define CC 384
#define NHE 12
#define HD 32
#define NTOK 32768  // BATCH*HDIM*WDIM
#define NBLK 2

typedef short short8 __attribute__((ext_vector_type(8)));
typedef float f32x4 __attribute__((ext_vector_type(4)));

__device__ __forceinline__ float bf2f(unsigned short u) {
  return __uint_as_float(((unsigned int)u) << 16);
}
__device__ __forceinline__ unsigned short f2bf(float f) {
  __hip_bfloat16 h = __float2bfloat16(f);
  return *reinterpret_cast<unsigned short*>(&h);
}
__device__ __forceinline__ float wave_sum(float s) {
#pragma unroll
  for (int o = 32; o; o >>= 1) s += __shfl_xor(s, o, 64);
  return s;
}
__device__ __forceinline__ float gelu_f(float x) {
  float y = 0.7978845608028654f * (x + 0.044715f * x * x * x);
  float t = 1.0f - 2.0f / (__expf(2.0f * y) + 1.0f);
  return 0.5f * x * (1.0f + t);
}
__device__ __forceinline__ int regid(int x) {
  // shifted-image region: rows 0..55 -> 0, 56..59 -> 1, 60..63 -> 2
  return x < 56 ? 0 : (x < 60 ? 1 : 2);
}

// ---- weight transpose + bf16 cast: src (K,N) f32 -> dst (N,K) bf16 ----
__global__ __launch_bounds__(256) void wconv_kernel(
    const float* __restrict__ src, unsigned short* __restrict__ dst, int K, int N) {
  int idx = blockIdx.x * 256 + threadIdx.x;
  int n = idx / K;
  int k = idx - n * K;
  dst[idx] = f2bf(src[(size_t)k * N + n]);
}

// ---- fused outer-LN + LN1 + shift + window partition ----
// y0 (fp32 token-major) = LN(xin)*og+ob ; abuf (bf16 window-major) = LN(y0)*n1g+n1b
__global__ __launch_bounds__(256) void ln_fused_kernel(
    const float* __restrict__ xin, const float* __restrict__ og,
    const float* __restrict__ ob, const float* __restrict__ n1g,
    const float* __restrict__ n1b, float* __restrict__ y0,
    unsigned short* __restrict__ abuf, int shift) {
  const int lane = threadIdx.x & 63;
  const int token = blockIdx.x * 4 + (threadIdx.x >> 6);
  const float* px = xin + (size_t)token * CC;
  float v[6];
#pragma unroll
  for (int j = 0; j < 6; ++j) v[j] = px[j * 64 + lane];
  // outer LN
  float s = 0.f;
#pragma unroll
  for (int j = 0; j < 6; ++j) s += v[j];
  s = wave_sum(s);
  float mean = s * (1.0f / CC);
  float q = 0.f;
#pragma unroll
  for (int j = 0; j < 6; ++j) { float d = v[j] - mean; q += d * d; }
  q = wave_sum(q);
  float rstd = rsqrtf(q * (1.0f / CC) + 1e-5f);
  float* py = y0 + (size_t)token * CC;
#pragma unroll
  for (int j = 0; j < 6; ++j) {
    int d = j * 64 + lane;
    float y = (v[j] - mean) * rstd * og[d] + ob[d];
    py[d] = y;
    v[j] = y;
  }
  // LN1
  s = 0.f;
#pragma unroll
  for (int j = 0; j < 6; ++j) s += v[j];
  s = wave_sum(s);
  float mean2 = s * (1.0f / CC);
  q = 0.f;
#pragma unroll
  for (int j = 0; j < 6; ++j) { float d = v[j] - mean2; q += d * d; }
  q = wave_sum(q);
  float rstd2 = rsqrtf(q * (1.0f / CC) + 1e-5f);
  // shifted window partition: shifted[r] = orig[(r+shift)%64] -> r = (hh-shift)&63
  int b = token >> 12;
  int hh = (token >> 6) & 63;
  int ww = token & 63;
  int r = (hh - shift) & 63;
  int c = (ww - shift) & 63;
  int wrow = (((b << 6) + ((r >> 3) << 3) + (c >> 3)) << 6) + ((r & 7) << 3) + (c & 7);
  unsigned short* pa = abuf + (size_t)wrow * CC;
#pragma unroll
  for (int j = 0; j < 6; ++j) {
    int d = j * 64 + lane;
    pa[d] = f2bf((v[j] - mean2) * rstd2 * n1g[d] + n1b[d]);
  }
}

// ---- LN2: x1 (fp32 token-major) -> abuf (bf16 token-major) ----
__global__ __launch_bounds__(256) void ln2_kernel(
    const float* __restrict__ x1, const float* __restrict__ g2,
    const float* __restrict__ b2, unsigned short* __restrict__ abuf) {
  const int lane = threadIdx.x & 63;
  const int token = blockIdx.x * 4 + (threadIdx.x >> 6);
  const float* px = x1 + (size_t)token * CC;
  float v[6];
#pragma unroll
  for (int j = 0; j < 6; ++j) v[j] = px[j * 64 + lane];
  float s = 0.f;
#pragma unroll
  for (int j = 0; j < 6; ++j) s += v[j];
  s = wave_sum(s);
  float mean = s * (1.0f / CC);
  float q = 0.f;
#pragma unroll
  for (int j = 0; j < 6; ++j) { float d = v[j] - mean; q += d * d; }
  q = wave_sum(q);
  float rstd = rsqrtf(q * (1.0f / CC) + 1e-5f);
  unsigned short* pa = abuf + (size_t)token * CC;
#pragma unroll
  for (int j = 0; j < 6; ++j) {
    int d = j * 64 + lane;
    pa[d] = f2bf((v[j] - mean) * rstd * g2[d] + b2[d]);
  }
}

// ---- windowed attention: one wave per (head, window) ----
__global__ __launch_bounds__(64) void attn_kernel(
    const unsigned short* __restrict__ qkv, const float* __restrict__ rpb,
    unsigned short* __restrict__ aout, int use_mask) {
  __shared__ __align__(16) float ks[64 * 36];
  __shared__ __align__(16) float vs[64 * 36];
  __shared__ float ss[64 * 65];
  const int h = blockIdx.x;
  const int wi = blockIdx.y;
  const int lane = threadIdx.x;
  size_t rowb = ((size_t)wi * 64 + lane) * (3 * CC) + h * HD;
  unsigned short tb[32];
  uint4* tb4 = (uint4*)tb;
  const uint4* pq = (const uint4*)(qkv + rowb);
  tb4[0] = pq[0]; tb4[1] = pq[1]; tb4[2] = pq[2]; tb4[3] = pq[3];
  float q[32];
#pragma unroll
  for (int d = 0; d < 32; ++d) q[d] = bf2f(tb[d]) * 0.17677669529663687f;
  const uint4* pk = (const uint4*)(qkv + rowb + CC);
  tb4[0] = pk[0]; tb4[1] = pk[1]; tb4[2] = pk[2]; tb4[3] = pk[3];
#pragma unroll
  for (int j = 0; j < 8; ++j)
    ((float4*)&ks[lane * 36])[j] =
        make_float4(bf2f(tb[4 * j]), bf2f(tb[4 * j + 1]), bf2f(tb[4 * j + 2]), bf2f(tb[4 * j + 3]));
  const uint4* pv = (const uint4*)(qkv + rowb + 2 * CC);
  tb4[0] = pv[0]; tb4[1] = pv[1]; tb4[2] = pv[2]; tb4[3] = pv[3];
#pragma unroll
  for (int j = 0; j < 8; ++j)
    ((float4*)&vs[lane * 36])[j] =
        make_float4(bf2f(tb[4 * j]), bf2f(tb[4 * j + 1]), bf2f(tb[4 * j + 2]), bf2f(tb[4 * j + 3]));
  __syncthreads();

  const int r1 = lane >> 3, c1 = lane & 7;
  const int wloc = wi & 63;
  const int wy = wloc >> 3, wx = wloc & 7;
  const int idn = regid(wy * 8 + r1) * 3 + regid(wx * 8 + c1);
  float mx = -1e30f;
  for (int m = 0; m < 64; ++m) {
    const float4* kr = (const float4*)&ks[m * 36];
    float s = 0.f;
#pragma unroll
    for (int j = 0; j < 8; ++j) {
      float4 kk = kr[j];
      s += q[4 * j] * kk.x + q[4 * j + 1] * kk.y + q[4 * j + 2] * kk.z + q[4 * j + 3] * kk.w;
    }
    int dr = r1 - (m >> 3) + 7;
    int dc = c1 - (m & 7) + 7;
    s += rpb[(dr * 15 + dc) * NHE + h];
    if (use_mask) {
      int idm = regid(wy * 8 + (m >> 3)) * 3 + regid(wx * 8 + (m & 7));
      s = (idm == idn) ? s : s - 100.0f;
    }
    ss[lane * 65 + m] = s;
    mx = fmaxf(mx, s);
  }
  float4 o4[8];
#pragma unroll
  for (int j = 0; j < 8; ++j) o4[j] = make_float4(0.f, 0.f, 0.f, 0.f);
  float sum = 0.f;
  for (int m = 0; m < 64; ++m) {
    float p = __expf(ss[lane * 65 + m] - mx);
    sum += p;
    const float4* vr = (const float4*)&vs[m * 36];
#pragma unroll
    for (int j = 0; j < 8; ++j) {
      float4 vv = vr[j];
      o4[j].x += p * vv.x; o4[j].y += p * vv.y; o4[j].z += p * vv.z; o4[j].w += p * vv.w;
    }
  }
  float inv = 1.0f / sum;
  unsigned short obts[32];
#pragma unroll
  for (int j = 0; j < 8; ++j) {
    obts[4 * j]     = f2bf(o4[j].x * inv);
    obts[4 * j + 1] = f2bf(o4[j].y * inv);
    obts[4 * j + 2] = f2bf(o4[j].z * inv);
    obts[4 * j + 3] = f2bf(o4[j].w * inv);
  }
  uint4* po = (uint4*)(aout + ((size_t)wi * 64 + lane) * CC + h * HD);
  const uint4* so = (const uint4*)obts;
  po[0] = so[0]; po[1] = so[1]; po[2] = so[2]; po[3] = so[3];
}

// ---- GEMM: C[M=32768, NN] = A[M,KK](bf16) @ Bt[NN,KK]^T(bf16) + bias, fused epilogues
// EPI 0: +bias -> bf16 (QKV)
// EPI 1: +bias, gelu -> bf16 (MLP1)
// EPI 2: +bias, un-window/un-shift scatter, + add0(y0) -> fp32 (PROJ -> x1)
// EPI 3: +bias, + add0(x1) + add1(xv_res) -> fp32 (MLP2 -> out)
template <int EPI, int NN, int KK>
__global__ __launch_bounds__(256, 2) void gemm_kernel(
    const unsigned short* __restrict__ A, const unsigned short* __restrict__ Bt,
    const float* __restrict__ bias, float* __restrict__ outf,
    unsigned short* __restrict__ outb, const float* __restrict__ add0,
    const float* __restrict__ add1, int shift) {
  __shared__ __align__(16) unsigned short As[128 * 72];
  __shared__ __align__(16) unsigned short Bs[128 * 72];
  const int tid = threadIdx.x;
  const int lane = tid & 63;
  const int wv = tid >> 6;
  const int wm = wv & 1, wn = wv >> 1;
  const int rowBase = blockIdx.y * 128;
  const int colBase = blockIdx.x * 128;
  f32x4 acc[4][4] = {};

  for (int k0 = 0; k0 < KK; k0 += 64) {
    __syncthreads();
#pragma unroll
    for (int it = 0; it < 4; ++it) {
      int e = it * 256 + tid;
      int row = e >> 3;
      int col = (e & 7) << 3;
      *(uint4*)&As[row * 72 + col] =
          *(const uint4*)(A + (size_t)(rowBase + row) * KK + k0 + col);
      *(uint4*)&Bs[row * 72 + col] =
          *(const uint4*)(Bt + (size_t)(colBase + row) * KK + k0 + col);
    }
    __syncthreads();
#pragma unroll
    for (int ksub = 0; ksub < 2; ++ksub) {
      int kb = ksub * 32 + (lane >> 4) * 8;
      short8 af[4], bfr[4];
#pragma unroll
      for (int im = 0; im < 4; ++im)
        af[im] = *(const short8*)&As[(wm * 64 + im * 16 + (lane & 15)) * 72 + kb];
#pragma unroll
      for (int in_ = 0; in_ < 4; ++in_)
        bfr[in_] = *(const short8*)&Bs[(wn * 64 + in_ * 16 + (lane & 15)) * 72 + kb];
#pragma unroll
      for (int im = 0; im < 4; ++im)
#pragma unroll
        for (int in_ = 0; in_ < 4; ++in_)
          acc[im][in_] = __builtin_amdgcn_mfma_f32_16x16x32_bf16(
              af[im], bfr[in_], acc[im][in_], 0, 0, 0);
    }
  }
  const int quad = lane >> 4;
  const int lc = lane & 15;
#pragma unroll
  for (int im = 0; im < 4; ++im) {
    int rb = rowBase + wm * 64 + im * 16 + quad * 4;
#pragma unroll
    for (int in_ = 0; in_ < 4; ++in_) {
      int gcol = colBase + wn * 64 + in_ * 16 + lc;
      float bv = bias[gcol];
#pragma unroll
      for (int r = 0; r < 4; ++r) {
        int grow = rb + r;
        float v = acc[im][in_][r] + bv;
        if (EPI == 0) {
          outb[(size_t)grow * NN + gcol] = f2bf(v);
        } else if (EPI == 1) {
          outb[(size_t)grow * NN + gcol] = f2bf(gelu_f(v));
        } else if (EPI == 2) {
          int b = grow >> 12;
          int wl = (grow >> 6) & 63;
          int t = grow & 63;
          int rr = ((wl >> 3) << 3) + (t >> 3);   // shifted row
          int cc = ((wl & 7) << 3) + (t & 7);     // shifted col
          int hh2 = (rr + shift) & 63;            // original row
          int ww2 = (cc + shift) & 63;            // original col
          size_t dst = ((size_t)((b << 6) + hh2) * 64 + ww2) * CC + gcol;
          outf[dst] = add0[dst] + v;
        } else {
          size_t dst = (size_t)grow * CC + gcol;
          outf[dst] = add0[dst] + add1[dst] + v;
        }
      }
    }
  }
}

extern "C" void kernel_launch(void* const* d_in, const int* in_sizes, int n_in,
                              void* d_out, int out_size, void* d_ws, size_t ws_size,
                              hipStream_t stream) {
  const float* x    = (const float*)d_in[0];
  const float* og   = (const float*)d_in[1];
  const float* ob   = (const float*)d_in[2];
  const float* n1g  = (const float*)d_in[3];
  const float* n1b  = (const float*)d_in[4];
  const float* n2g  = (const float*)d_in[5];
  const float* n2b  = (const float*)d_in[6];
  const float* qkvw = (const float*)d_in[7];
  const float* qkvb = (const float*)d_in[8];
  const float* pw   = (const float*)d_in[9];
  const float* pb   = (const float*)d_in[10];
  const float* w1   = (const float*)d_in[11];
  const float* b1   = (const float*)d_in[12];
  const float* w2   = (const float*)d_in[13];
  const float* b2   = (const float*)d_in[14];
  const float* rpb  = (const float*)d_in[15];
  float* out = (float*)d_out;

  char* ws = (char*)d_ws;
  float* y0             = (float*)(ws);                       // 50331648 B
  float* x1             = (float*)(ws + 50331648);            // 50331648 B
  unsigned short* a_bf  = (unsigned short*)(ws + 100663296);  // 25165824 B
  unsigned short* at_bf = (unsigned short*)(ws + 125829120);  // 25165824 B
  unsigned short* big_bf= (unsigned short*)(ws + 150994944);  // 100663296 B (qkv/mlp1 union)
  unsigned short* wt    = (unsigned short*)(ws + 251658240);  // 7077888 B

  // per-launch weight transpose+cast (ws is re-poisoned every call)
  for (int i = 0; i < NBLK; ++i) {
    unsigned short* wq = wt + (size_t)i * 1769472;
    wconv_kernel<<<442368 / 256, 256, 0, stream>>>(qkvw + (size_t)i * 442368, wq, 384, 1152);
    wconv_kernel<<<147456 / 256, 256, 0, stream>>>(pw + (size_t)i * 147456, wq + 442368, 384, 384);
    wconv_kernel<<<589824 / 256, 256, 0, stream>>>(w1 + (size_t)i * 589824, wq + 589824, 384, 1536);
    wconv_kernel<<<589824 / 256, 256, 0, stream>>>(w2 + (size_t)i * 589824, wq + 1179648, 1536, 384);
  }

  for (int i = 0; i < NBLK; ++i) {
    const float* xin = (i == 0) ? x : out;
    int shift = (i & 1) ? 4 : 0;
    unsigned short* wq = wt + (size_t)i * 1769472;
    ln_fused_kernel<<<8192, 256, 0, stream>>>(xin, og + i * 384, ob + i * 384,
                                              n1g + i * 384, n1b + i * 384, y0, a_bf, shift);
    gemm_kernel<0, 1152, 384><<<dim3(9, 256), 256, 0, stream>>>(
        a_bf, wq, qkvb + i * 1152, nullptr, big_bf, nullptr, nullptr, 0);
    attn_kernel<<<dim3(12, 512), 64, 0, stream>>>(big_bf, rpb + i * 2700, at_bf, shift ? 1 : 0);
    gemm_kernel<2, 384, 384><<<dim3(3, 256), 256, 0, stream>>>(
        at_bf, wq + 442368, pb + i * 384, x1, nullptr, y0, nullptr, shift);
    ln2_kernel<<<8192, 256, 0, stream>>>(x1, n2g + i * 384, n2b + i * 384, a_bf);
    gemm_kernel<1, 1536, 384><<<dim3(12, 256), 256, 0, stream>>>(
        a_bf, wq + 589824, b1 + i * 1536, nullptr, big_bf, nullptr, nullptr, 0);
    gemm_kernel<3, 384, 1536><<<dim3(3, 256), 256, 0, stream>>>(
        big_bf, wq + 1179648, b2 + i * 384, out, nullptr, x1, xin, 0);
  }
}

// Round 2
// 755.871 us; speedup vs baseline: 1.2836x; 1.2836x over previous
//
#include <hip/hip_runtime.h>
#include <hip/hip_bf16.h>

#define BATCH 8
#define HDIM 64
#define WDIM 64
#define CC 384
#define NHE 12
#define HD 32
#define NTOK 32768  // BATCH*HDIM*WDIM
#define NBLK 2

typedef short short8 __attribute__((ext_vector_type(8)));
typedef float f32x4 __attribute__((ext_vector_type(4)));

__device__ __forceinline__ float bf2f(unsigned short u) {
  return __uint_as_float(((unsigned int)u) << 16);
}
__device__ __forceinline__ unsigned short f2bf(float f) {
  __hip_bfloat16 h = __float2bfloat16(f);
  return *reinterpret_cast<unsigned short*>(&h);
}
__device__ __forceinline__ float wave_sum(float s) {
#pragma unroll
  for (int o = 32; o; o >>= 1) s += __shfl_xor(s, o, 64);
  return s;
}
__device__ __forceinline__ float gelu_f(float x) {
  float y = 0.7978845608028654f * (x + 0.044715f * x * x * x);
  float t = 1.0f - 2.0f / (__expf(2.0f * y) + 1.0f);
  return 0.5f * x * (1.0f + t);
}
__device__ __forceinline__ int regid(int x) {
  // shifted-image region: rows 0..55 -> 0, 56..59 -> 1, 60..63 -> 2
  return x < 56 ? 0 : (x < 60 ? 1 : 2);
}

// ---- weight transpose + bf16 cast: src (K,N) f32 -> dst (N,K) bf16 ----
__global__ __launch_bounds__(256) void wconv_kernel(
    const float* __restrict__ src, unsigned short* __restrict__ dst, int K, int N) {
  int idx = blockIdx.x * 256 + threadIdx.x;
  int n = idx / K;
  int k = idx - n * K;
  dst[idx] = f2bf(src[(size_t)k * N + n]);
}

// ---- bias table prep: biasT[h][n][m] = rpb[relidx(n,m)*12 + h] (one swin block) ----
__global__ __launch_bounds__(256) void bias_prep_kernel(
    const float* __restrict__ rpb, float* __restrict__ biasT) {
  int idx = blockIdx.x * 256 + threadIdx.x;  // 12*64*64 = 49152
  int m = idx & 63;
  int n = (idx >> 6) & 63;
  int h = idx >> 12;
  int dr = (n >> 3) - (m >> 3) + 7;
  int dc = (n & 7) - (m & 7) + 7;
  biasT[idx] = rpb[(dr * 15 + dc) * NHE + h];
}

// ---- fused outer-LN + LN1 + shift + window partition ----
__global__ __launch_bounds__(256) void ln_fused_kernel(
    const float* __restrict__ xin, const float* __restrict__ og,
    const float* __restrict__ ob, const float* __restrict__ n1g,
    const float* __restrict__ n1b, float* __restrict__ y0,
    unsigned short* __restrict__ abuf, int shift) {
  const int lane = threadIdx.x & 63;
  const int token = blockIdx.x * 4 + (threadIdx.x >> 6);
  const float* px = xin + (size_t)token * CC;
  float v[6];
#pragma unroll
  for (int j = 0; j < 6; ++j) v[j] = px[j * 64 + lane];
  float s = 0.f;
#pragma unroll
  for (int j = 0; j < 6; ++j) s += v[j];
  s = wave_sum(s);
  float mean = s * (1.0f / CC);
  float q = 0.f;
#pragma unroll
  for (int j = 0; j < 6; ++j) { float d = v[j] - mean; q += d * d; }
  q = wave_sum(q);
  float rstd = rsqrtf(q * (1.0f / CC) + 1e-5f);
  float* py = y0 + (size_t)token * CC;
#pragma unroll
  for (int j = 0; j < 6; ++j) {
    int d = j * 64 + lane;
    float y = (v[j] - mean) * rstd * og[d] + ob[d];
    py[d] = y;
    v[j] = y;
  }
  s = 0.f;
#pragma unroll
  for (int j = 0; j < 6; ++j) s += v[j];
  s = wave_sum(s);
  float mean2 = s * (1.0f / CC);
  q = 0.f;
#pragma unroll
  for (int j = 0; j < 6; ++j) { float d = v[j] - mean2; q += d * d; }
  q = wave_sum(q);
  float rstd2 = rsqrtf(q * (1.0f / CC) + 1e-5f);
  int b = token >> 12;
  int hh = (token >> 6) & 63;
  int ww = token & 63;
  int r = (hh - shift) & 63;
  int c = (ww - shift) & 63;
  int wrow = (((b << 6) + ((r >> 3) << 3) + (c >> 3)) << 6) + ((r & 7) << 3) + (c & 7);
  unsigned short* pa = abuf + (size_t)wrow * CC;
#pragma unroll
  for (int j = 0; j < 6; ++j) {
    int d = j * 64 + lane;
    pa[d] = f2bf((v[j] - mean2) * rstd2 * n1g[d] + n1b[d]);
  }
}

// ---- LN2: x1 (fp32 token-major) -> abuf (bf16 token-major) ----
__global__ __launch_bounds__(256) void ln2_kernel(
    const float* __restrict__ x1, const float* __restrict__ g2,
    const float* __restrict__ b2, unsigned short* __restrict__ abuf) {
  const int lane = threadIdx.x & 63;
  const int token = blockIdx.x * 4 + (threadIdx.x >> 6);
  const float* px = x1 + (size_t)token * CC;
  float v[6];
#pragma unroll
  for (int j = 0; j < 6; ++j) v[j] = px[j * 64 + lane];
  float s = 0.f;
#pragma unroll
  for (int j = 0; j < 6; ++j) s += v[j];
  s = wave_sum(s);
  float mean = s * (1.0f / CC);
  float q = 0.f;
#pragma unroll
  for (int j = 0; j < 6; ++j) { float d = v[j] - mean; q += d * d; }
  q = wave_sum(q);
  float rstd = rsqrtf(q * (1.0f / CC) + 1e-5f);
  unsigned short* pa = abuf + (size_t)token * CC;
#pragma unroll
  for (int j = 0; j < 6; ++j) {
    int d = j * 64 + lane;
    pa[d] = f2bf((v[j] - mean) * rstd * g2[d] + b2[d]);
  }
}

// ---- MFMA windowed attention ----
// Block: 256 threads = 4 waves. Wave wv handles (window wi, head hg*4+wv).
// S^T = K*Q^T (acc init = bias), softmax over rows(m) in C-layout,
// P -> LDS (bf16, A-layout readable), O = P*V with V^T staged in LDS.
// Per-wave LDS: P/O union 9216 B + Vt 4608 B = 13824 B; block = 55296 B.
__global__ __launch_bounds__(256, 2) void attn_mfma_kernel(
    const unsigned short* __restrict__ qkv, const float* __restrict__ biasT,
    unsigned short* __restrict__ aout, int use_mask) {
  __shared__ char smem[55296];
  const int tid = threadIdx.x;
  const int wv = tid >> 6;
  const int lane = tid & 63;
  const int l0 = lane & 15;
  const int q = lane >> 4;
  const int wi = blockIdx.x / 3;
  const int hg = blockIdx.x - wi * 3;
  const int h = hg * 4 + wv;

  unsigned short* Pl = (unsigned short*)(smem + wv * 13824);       // 64 x 72 bf16
  unsigned short* Vt = (unsigned short*)(smem + wv * 13824 + 9216); // 32 x 72 bf16

  const unsigned short* qbase = qkv + (size_t)(wi * 64) * 1152 + h * HD;

  // K fragments (A operand, rows m) and Q fragments (B operand, cols n)
  short8 kf[4], qf[4];
#pragma unroll
  for (int mt = 0; mt < 4; ++mt)
    kf[mt] = *(const short8*)(qbase + (size_t)(16 * mt + l0) * 1152 + CC + 8 * q);
#pragma unroll
  for (int nt = 0; nt < 4; ++nt)
    qf[nt] = *(const short8*)(qbase + (size_t)(16 * nt + l0) * 1152 + 8 * q);

  // acc init = bias (C-layout: row m = 4q+r+16mt, col n = l0+16nt)
  f32x4 acc[4][4];
  const float* bh = biasT + h * 4096;
#pragma unroll
  for (int mt = 0; mt < 4; ++mt)
#pragma unroll
    for (int nt = 0; nt < 4; ++nt)
      acc[mt][nt] = *(const f32x4*)(bh + (l0 + 16 * nt) * 64 + 16 * mt + 4 * q);

  // stage V^T into LDS: lane loads V row m=lane (32 bf16 = 64 B), writes transposed
  unsigned short varr[32];
  {
    const uint4* pv = (const uint4*)(qbase + (size_t)lane * 1152 + 2 * CC);
    uint4* t4 = (uint4*)varr;
    t4[0] = pv[0]; t4[1] = pv[1]; t4[2] = pv[2]; t4[3] = pv[3];
#pragma unroll
    for (int d = 0; d < 32; ++d) Vt[d * 72 + lane] = varr[d];
  }

  // S^T MFMAs
#pragma unroll
  for (int mt = 0; mt < 4; ++mt)
#pragma unroll
    for (int nt = 0; nt < 4; ++nt)
      acc[mt][nt] = __builtin_amdgcn_mfma_f32_16x16x32_bf16(kf[mt], qf[nt], acc[mt][nt], 0, 0, 0);

  // shift mask
  if (use_mask) {
    int wloc = wi & 63;
    int wy = (wloc >> 3) * 8, wx = (wloc & 7) * 8;
    int idn[4], idm[16];
#pragma unroll
    for (int nt = 0; nt < 4; ++nt) {
      int n = l0 + 16 * nt;
      idn[nt] = regid(wy + (n >> 3)) * 3 + regid(wx + (n & 7));
    }
#pragma unroll
    for (int mt = 0; mt < 4; ++mt)
#pragma unroll
      for (int r = 0; r < 4; ++r) {
        int m = 16 * mt + 4 * q + r;
        idm[mt * 4 + r] = regid(wy + (m >> 3)) * 3 + regid(wx + (m & 7));
      }
#pragma unroll
    for (int mt = 0; mt < 4; ++mt)
#pragma unroll
      for (int nt = 0; nt < 4; ++nt)
#pragma unroll
        for (int r = 0; r < 4; ++r)
          acc[mt][nt][r] += (idm[mt * 4 + r] == idn[nt]) ? 0.0f : -100.0f;
  }

  // softmax over m: 16 in-lane values per column + cross-quad shfl
  float mx[4], sm[4], inv[4];
#pragma unroll
  for (int nt = 0; nt < 4; ++nt) {
    float m0 = -1e30f;
#pragma unroll
    for (int mt = 0; mt < 4; ++mt)
#pragma unroll
      for (int r = 0; r < 4; ++r) m0 = fmaxf(m0, acc[mt][nt][r]);
    m0 = fmaxf(m0, __shfl_xor(m0, 16, 64));
    m0 = fmaxf(m0, __shfl_xor(m0, 32, 64));
    mx[nt] = m0;
  }
#pragma unroll
  for (int nt = 0; nt < 4; ++nt) {
    float s0 = 0.f;
#pragma unroll
    for (int mt = 0; mt < 4; ++mt)
#pragma unroll
      for (int r = 0; r < 4; ++r) {
        float e = __expf(acc[mt][nt][r] - mx[nt]);
        acc[mt][nt][r] = e;
        s0 += e;
      }
    s0 += __shfl_xor(s0, 16, 64);
    s0 += __shfl_xor(s0, 32, 64);
    sm[nt] = s0;
    inv[nt] = 1.0f / s0;
  }

  // write P (already normalized) to LDS: P[n][m], row stride 72 bf16
#pragma unroll
  for (int mt = 0; mt < 4; ++mt)
#pragma unroll
    for (int nt = 0; nt < 4; ++nt) {
      unsigned int lo = (unsigned int)f2bf(acc[mt][nt][0] * inv[nt]) |
                        ((unsigned int)f2bf(acc[mt][nt][1] * inv[nt]) << 16);
      unsigned int hi = (unsigned int)f2bf(acc[mt][nt][2] * inv[nt]) |
                        ((unsigned int)f2bf(acc[mt][nt][3] * inv[nt]) << 16);
      unsigned int* dst = (unsigned int*)(Pl + (l0 + 16 * nt) * 72 + 16 * mt + 4 * q);
      dst[0] = lo;
      dst[1] = hi;
    }
  __syncthreads();

  // O = P*V : A = P rows n, B = V (read via Vt rows d)
  f32x4 oacc[4][2] = {};
#pragma unroll
  for (int kt = 0; kt < 2; ++kt) {
    short8 pa[4], vb[2];
#pragma unroll
    for (int nt = 0; nt < 4; ++nt)
      pa[nt] = *(const short8*)(Pl + (l0 + 16 * nt) * 72 + 8 * q + 32 * kt);
#pragma unroll
    for (int dt = 0; dt < 2; ++dt)
      vb[dt] = *(const short8*)(Vt + (l0 + 16 * dt) * 72 + 8 * q + 32 * kt);
#pragma unroll
    for (int nt = 0; nt < 4; ++nt)
#pragma unroll
      for (int dt = 0; dt < 2; ++dt)
        oacc[nt][dt] = __builtin_amdgcn_mfma_f32_16x16x32_bf16(pa[nt], vb[dt], oacc[nt][dt], 0, 0, 0);
  }
  __syncthreads();

  // transpose O through LDS (f32, stride 36) for coalesced 64B/lane stores
  float* Ol = (float*)Pl;
#pragma unroll
  for (int nt = 0; nt < 4; ++nt)
#pragma unroll
    for (int dt = 0; dt < 2; ++dt)
#pragma unroll
      for (int r = 0; r < 4; ++r)
        Ol[(16 * nt + 4 * q + r) * 36 + l0 + 16 * dt] = oacc[nt][dt][r];
  __syncthreads();
  unsigned short ob[32];
#pragma unroll
  for (int j = 0; j < 32; ++j) ob[j] = f2bf(Ol[lane * 36 + j]);
  uint4* po = (uint4*)(aout + ((size_t)wi * 64 + lane) * CC + h * HD);
  const uint4* so = (const uint4*)ob;
  po[0] = so[0]; po[1] = so[1]; po[2] = so[2]; po[3] = so[3];
}

// ---- GEMM: C[M=32768, NN] = A[M,KK](bf16) @ Bt[NN,KK]^T(bf16) + bias, fused epilogues
// EPI 0: +bias, scale q-cols by 1/sqrt(hd) -> bf16 (QKV)
// EPI 1: +bias, gelu -> bf16 (MLP1)
// EPI 2: +bias, un-window/un-shift scatter, + add0(y0) -> fp32 (PROJ -> x1)
// EPI 3: +bias, + add0(x1) + add1(xv_res) -> fp32 (MLP2 -> out)
template <int EPI, int NN, int KK>
__global__ __launch_bounds__(256, 2) void gemm_kernel(
    const unsigned short* __restrict__ A, const unsigned short* __restrict__ Bt,
    const float* __restrict__ bias, float* __restrict__ outf,
    unsigned short* __restrict__ outb, const float* __restrict__ add0,
    const float* __restrict__ add1, int shift) {
  __shared__ __align__(16) unsigned short As[128 * 72];
  __shared__ __align__(16) unsigned short Bs[128 * 72];
  const int tid = threadIdx.x;
  const int lane = tid & 63;
  const int wv = tid >> 6;
  const int wm = wv & 1, wn = wv >> 1;
  const int rowBase = blockIdx.y * 128;
  const int colBase = blockIdx.x * 128;
  f32x4 acc[4][4] = {};

  for (int k0 = 0; k0 < KK; k0 += 64) {
    __syncthreads();
#pragma unroll
    for (int it = 0; it < 4; ++it) {
      int e = it * 256 + tid;
      int row = e >> 3;
      int col = (e & 7) << 3;
      *(uint4*)&As[row * 72 + col] =
          *(const uint4*)(A + (size_t)(rowBase + row) * KK + k0 + col);
      *(uint4*)&Bs[row * 72 + col] =
          *(const uint4*)(Bt + (size_t)(colBase + row) * KK + k0 + col);
    }
    __syncthreads();
#pragma unroll
    for (int ksub = 0; ksub < 2; ++ksub) {
      int kb = ksub * 32 + (lane >> 4) * 8;
      short8 af[4], bfr[4];
#pragma unroll
      for (int im = 0; im < 4; ++im)
        af[im] = *(const short8*)&As[(wm * 64 + im * 16 + (lane & 15)) * 72 + kb];
#pragma unroll
      for (int in_ = 0; in_ < 4; ++in_)
        bfr[in_] = *(const short8*)&Bs[(wn * 64 + in_ * 16 + (lane & 15)) * 72 + kb];
#pragma unroll
      for (int im = 0; im < 4; ++im)
#pragma unroll
        for (int in_ = 0; in_ < 4; ++in_)
          acc[im][in_] = __builtin_amdgcn_mfma_f32_16x16x32_bf16(
              af[im], bfr[in_], acc[im][in_], 0, 0, 0);
    }
  }
  const int quad = lane >> 4;
  const int lc = lane & 15;
#pragma unroll
  for (int im = 0; im < 4; ++im) {
    int rb = rowBase + wm * 64 + im * 16 + quad * 4;
#pragma unroll
    for (int in_ = 0; in_ < 4; ++in_) {
      int gcol = colBase + wn * 64 + in_ * 16 + lc;
      float bv = bias[gcol];
#pragma unroll
      for (int r = 0; r < 4; ++r) {
        int grow = rb + r;
        float v = acc[im][in_][r] + bv;
        if (EPI == 0) {
          if (gcol < CC) v *= 0.17677669529663687f;  // fold q-scale into QKV
          outb[(size_t)grow * NN + gcol] = f2bf(v);
        } else if (EPI == 1) {
          outb[(size_t)grow * NN + gcol] = f2bf(gelu_f(v));
        } else if (EPI == 2) {
          int b = grow >> 12;
          int wl = (grow >> 6) & 63;
          int t = grow & 63;
          int rr = ((wl >> 3) << 3) + (t >> 3);
          int cc = ((wl & 7) << 3) + (t & 7);
          int hh2 = (rr + shift) & 63;
          int ww2 = (cc + shift) & 63;
          size_t dst = ((size_t)((b << 6) + hh2) * 64 + ww2) * CC + gcol;
          outf[dst] = add0[dst] + v;
        } else {
          size_t dst = (size_t)grow * CC + gcol;
          outf[dst] = add0[dst] + add1[dst] + v;
        }
      }
    }
  }
}

extern "C" void kernel_launch(void* const* d_in, const int* in_sizes, int n_in,
                              void* d_out, int out_size, void* d_ws, size_t ws_size,
                              hipStream_t stream) {
  const float* x    = (const float*)d_in[0];
  const float* og   = (const float*)d_in[1];
  const float* ob   = (const float*)d_in[2];
  const float* n1g  = (const float*)d_in[3];
  const float* n1b  = (const float*)d_in[4];
  const float* n2g  = (const float*)d_in[5];
  const float* n2b  = (const float*)d_in[6];
  const float* qkvw = (const float*)d_in[7];
  const float* qkvb = (const float*)d_in[8];
  const float* pw   = (const float*)d_in[9];
  const float* pb   = (const float*)d_in[10];
  const float* w1   = (const float*)d_in[11];
  const float* b1   = (const float*)d_in[12];
  const float* w2   = (const float*)d_in[13];
  const float* b2   = (const float*)d_in[14];
  const float* rpb  = (const float*)d_in[15];
  float* out = (float*)d_out;

  char* ws = (char*)d_ws;
  float* y0             = (float*)(ws);                       // 50331648 B
  float* x1             = (float*)(ws + 50331648);            // 50331648 B
  unsigned short* a_bf  = (unsigned short*)(ws + 100663296);  // 25165824 B
  unsigned short* at_bf = (unsigned short*)(ws + 125829120);  // 25165824 B
  unsigned short* big_bf= (unsigned short*)(ws + 150994944);  // 100663296 B (qkv/mlp1 union)
  unsigned short* wt    = (unsigned short*)(ws + 251658240);  // 7077888 B
  // biasT lives in the tail of big_bf after the 75.5MB qkv region; it is
  // computed after the qkv GEMM and dead before mlp1 overwrites it.
  float* biasT          = (float*)(ws + 150994944 + 75497472);  // 196608 B

  for (int i = 0; i < NBLK; ++i) {
    unsigned short* wq = wt + (size_t)i * 1769472;
    wconv_kernel<<<442368 / 256, 256, 0, stream>>>(qkvw + (size_t)i * 442368, wq, 384, 1152);
    wconv_kernel<<<147456 / 256, 256, 0, stream>>>(pw + (size_t)i * 147456, wq + 442368, 384, 384);
    wconv_kernel<<<589824 / 256, 256, 0, stream>>>(w1 + (size_t)i * 589824, wq + 589824, 384, 1536);
    wconv_kernel<<<589824 / 256, 256, 0, stream>>>(w2 + (size_t)i * 589824, wq + 1179648, 1536, 384);
  }

  for (int i = 0; i < NBLK; ++i) {
    const float* xin = (i == 0) ? x : out;
    int shift = (i & 1) ? 4 : 0;
    unsigned short* wq = wt + (size_t)i * 1769472;
    ln_fused_kernel<<<8192, 256, 0, stream>>>(xin, og + i * 384, ob + i * 384,
                                              n1g + i * 384, n1b + i * 384, y0, a_bf, shift);
    gemm_kernel<0, 1152, 384><<<dim3(9, 256), 256, 0, stream>>>(
        a_bf, wq, qkvb + i * 1152, nullptr, big_bf, nullptr, nullptr, 0);
    bias_prep_kernel<<<192, 256, 0, stream>>>(rpb + i * 2700, biasT);
    attn_mfma_kernel<<<1536, 256, 0, stream>>>(big_bf, biasT, at_bf, shift ? 1 : 0);
    gemm_kernel<2, 384, 384><<<dim3(3, 256), 256, 0, stream>>>(
        at_bf, wq + 442368, pb + i * 384, x1, nullptr, y0, nullptr, shift);
    ln2_kernel<<<8192, 256, 0, stream>>>(x1, n2g + i * 384, n2b + i * 384, a_bf);
    gemm_kernel<1, 1536, 384><<<dim3(12, 256), 256, 0, stream>>>(
        a_bf, wq + 589824, b1 + i * 1536, nullptr, big_bf, nullptr, nullptr, 0);
    gemm_kernel<3, 384, 1536><<<dim3(3, 256), 256, 0, stream>>>(
        big_bf, wq + 1179648, b2 + i * 384, out, nullptr, x1, xin, 0);
  }
}